// Round 9
// baseline (919.478 us; speedup 1.0000x reference)
//
#include <hip/hip_runtime.h>
#include <stdint.h>

// Problem constants (match reference)
#define NB   8
#define NP   16384
#define NG   512      // NUM_GROUPS
#define GS   32       // GROUP_SIZE
#define UPK  512      // UPSCALE_K
#define CTX  256      // CONTEXT

// float32 output layout (flat element offsets):
// groups (8,256,32,4) | centers (8,256,4) | emb_mask (8,256) | point_mask (8,256,32)
#define OFF_CENTERS (NB*CTX*GS*4)            // 262144
#define OFF_EMB     (OFF_CENTERS + NB*CTX*4) // 270336
#define OFF_PMASK   (OFF_EMB + NB*CTX)       // 272384

typedef unsigned long long u64;
typedef unsigned int u32;

// Monotonic float->uint key (full-range; needed for energies which can be <0)
__device__ __forceinline__ u32 fkey(float f) {
  union { float f; u32 u; } v; v.f = f;
  u32 s = v.u;
  return s ^ ((s & 0x80000000u) ? 0xFFFFFFFFu : 0x80000000u);
}

// Strictly-unfused f32 squared distance, op order = np: ((dx*dx+dy*dy)+dz*dz).
__device__ __forceinline__ float dist2(float ax, float ay, float az,
                                       float bx, float by, float bz) {
  float dx = __fsub_rn(ax, bx);
  float dy = __fsub_rn(ay, by);
  float dz = __fsub_rn(az, bz);
  return __fadd_rn(__fadd_rn(__fmul_rn(dx, dx), __fmul_rn(dy, dy)),
                   __fmul_rn(dz, dz));
}

// Packed f32 (VOP3P) ops — guaranteed per-half IEEE rn, never contracted.
__device__ __forceinline__ float2 pk_add(float2 a, float2 b) {
  float2 r;
  asm("v_pk_add_f32 %0, %1, %2" : "=v"(r) : "v"(a), "v"(b));
  return r;
}
__device__ __forceinline__ float2 pk_mul(float2 a, float2 b) {
  float2 r;
  asm("v_pk_mul_f32 %0, %1, %2" : "=v"(r) : "v"(a), "v"(b));
  return r;
}

// u32 max-combine with DPP-moved copy (bound_ctrl=false keeps own value for
// invalid sources -> max no-op there). 2 instr/step (mov_dpp + v_max_u32).
template<int CTRL, int RM>
__device__ __forceinline__ u32 dpp_max_u32(u32 k) {
  u32 m = (u32)__builtin_amdgcn_update_dpp((int)k, (int)k, CTRL, RM, 0xf, false);
  return m > k ? m : k;
}

// ---------------------------------------------------------------------------
// Kernel 1: farthest point sampling. One block per batch, 511 sequential
// argmax steps on one CU. Inner loop: packed-f32 distances (bit-exact,
// unfused), scalar v_min mind update — 10 instr per point pair. Argmax is
// split: (a) f32 tree max + 32-bit DPP wave/block max (dists >= 0 so f32
// bits are u32-monotonic; no -0/NaN possible), (b) only bit-equal threads
// (~1 wave) scan for their first matching slot and atomicMin the global
// index into LDS -> exact np.argmax first-occurrence. Invalid points alias
// p[0]: their mind == p0's mind (0 after iter 1, center0 = idx 0) and their
// indices are >= len, so min-index resolution always lands on a valid point.
// ---------------------------------------------------------------------------
#define FPS_T 1024
#define PPT   (NP / FPS_T)   // 16 points per thread, 8 float2 pairs

__global__ __launch_bounds__(FPS_T)
void fps_kernel(const float4* __restrict__ pts, const int* __restrict__ lengths,
                float4* __restrict__ centers_ws, int* __restrict__ group_len,
                float* __restrict__ out)
{
  const int b    = blockIdx.x;
  const int tid  = threadIdx.x;
  const int lane = tid & 63;
  const int wave = tid >> 6;
  const float4* p = pts + (size_t)b * NP;
  const int len = lengths[b];
  if (tid == 0) group_len[b] = 0;

  const float4 q0 = p[0];
  float2 px2[PPT/2], py2[PPT/2], pz2[PPT/2], mind2[PPT/2];
#pragma unroll
  for (int h = 0; h < PPT/2; h++) {
    int ia = tid + (2*h) * FPS_T, ib = tid + (2*h+1) * FPS_T;
    float4 qa = p[ia]; if (ia >= len) qa = q0;   // invalid -> alias of p[0]
    float4 qb = p[ib]; if (ib >= len) qb = q0;
    px2[h] = make_float2(qa.x, qb.x);
    py2[h] = make_float2(qa.y, qb.y);
    pz2[h] = make_float2(qa.z, qb.z);
    mind2[h] = make_float2(1e10f, 1e10f);
  }

  __shared__ u32 smax[2][16];
  __shared__ u32 s_widx[2];
  __shared__ int s_centers[NG];
  if (tid == 0) {
    s_centers[0] = 0;                 // start index = 0
    s_widx[0] = 0xFFFFFFFFu;
    s_widx[1] = 0xFFFFFFFFu;
  }

  int last = 0;
  for (int it = 1; it < NG; it++) {
    const int buf = it & 1;
    float4 lp = p[last];              // broadcast load (L2-served)
    float2 nlx = make_float2(-lp.x, -lp.x);   // a + (-b) == a - b (IEEE)
    float2 nly = make_float2(-lp.y, -lp.y);
    float2 nlz = make_float2(-lp.z, -lp.z);
#pragma unroll
    for (int h = 0; h < PPT/2; h++) {
      float2 dx = pk_add(px2[h], nlx);
      float2 dy = pk_add(py2[h], nly);
      float2 dz = pk_add(pz2[h], nlz);
      float2 sx = pk_mul(dx, dx);
      float2 sy = pk_mul(dy, dy);
      float2 sz = pk_mul(dz, dz);
      float2 v  = pk_add(sx, sy);
      float2 d2 = pk_add(v, sz);
      float2 m = mind2[h];
      m.x = fminf(m.x, d2.x);
      m.y = fminf(m.y, d2.y);
      mind2[h] = m;
    }
    // Per-thread max of 16 minds (compiler fuses fmaxf chains to v_max3)
    float t01 = fmaxf(fmaxf(mind2[0].x, mind2[0].y),
                      fmaxf(mind2[1].x, mind2[1].y));
    float t23 = fmaxf(fmaxf(mind2[2].x, mind2[2].y),
                      fmaxf(mind2[3].x, mind2[3].y));
    float t45 = fmaxf(fmaxf(mind2[4].x, mind2[4].y),
                      fmaxf(mind2[5].x, mind2[5].y));
    float t67 = fmaxf(fmaxf(mind2[6].x, mind2[6].y),
                      fmaxf(mind2[7].x, mind2[7].y));
    float tm = fmaxf(fmaxf(t01, t23), fmaxf(t45, t67));
    u32 kb = __float_as_uint(tm);     // >=0, +0 only -> u32 order == f32 order

    kb = dpp_max_u32<0x111, 0xf>(kb); // row_shr:1
    kb = dpp_max_u32<0x112, 0xf>(kb); // row_shr:2
    kb = dpp_max_u32<0x114, 0xf>(kb); // row_shr:4
    kb = dpp_max_u32<0x118, 0xf>(kb); // row_shr:8
    kb = dpp_max_u32<0x142, 0xa>(kb); // row_bcast:15
    kb = dpp_max_u32<0x143, 0xc>(kb); // row_bcast:31 -> lane63 = wave max
    if (lane == 63) smax[buf][wave] = kb;
    __syncthreads();                  // barrier 1

    u32 k2 = smax[buf][lane & 15];    // slots replicated every 16 lanes
    k2 = dpp_max_u32<0x111, 0xf>(k2);
    k2 = dpp_max_u32<0x112, 0xf>(k2);
    k2 = dpp_max_u32<0x114, 0xf>(k2);
    k2 = dpp_max_u32<0x118, 0xf>(k2); // lane15 of each row = block max
    u32 gmax = (u32)__builtin_amdgcn_readlane((int)k2, 15);

    if (__float_as_uint(tm) == gmax) {          // ~1 wave enters
      u32 found = 0xFFFFFFFFu;
#pragma unroll
      for (int h = 0; h < PPT/2; h++) {         // first match = min gidx
        u32 bx = __float_as_uint(mind2[h].x);
        u32 by = __float_as_uint(mind2[h].y);
        if (bx == gmax && found == 0xFFFFFFFFu) found = (u32)(tid + ((2*h) << 10));
        if (by == gmax && found == 0xFFFFFFFFu) found = (u32)(tid + ((2*h+1) << 10));
      }
      if (found != 0xFFFFFFFFu) atomicMin(&s_widx[buf], found);
    }
    __syncthreads();                  // barrier 2
    last = (int)(s_widx[buf] & (NP - 1));
    if (tid == 0) s_widx[buf ^ 1] = 0xFFFFFFFFu;  // re-init for iter it+2
    if (tid == 0) s_centers[it] = last;
  }
  __syncthreads();

  if (tid < NG) {
    int ci = s_centers[tid] & (NP - 1);
    float4 q = p[ci];
    centers_ws[b * NG + tid] = q;
    if (tid < CTX) {
      ((float4*)(out + OFF_CENTERS))[b * CTX + tid] = q;
    }
  }
}

// ---------------------------------------------------------------------------
// Kernel 2: ball query (first-512-by-index candidates, strict-f32 test)
// + top-32 by energy. Swizzled so batch b owns XCD b (blk&7) -> per-XCD
// L2-resident point data. g >= CTX groups take a count-only fast path.
// Heavy path: ballot masks -> shfl_up prefix scan (1 barrier) -> compact ->
// single-wave barrier-free top-32 (u64 key = fkeyE<<32 | ~pos).
// ---------------------------------------------------------------------------
#define BQ_T 256

__global__ __launch_bounds__(BQ_T)
void group_kernel(const float4* __restrict__ pts, const int* __restrict__ lengths,
                  const float4* __restrict__ centers_ws, int* __restrict__ group_len,
                  float* __restrict__ out)
{
  const int blk  = blockIdx.x;
  const int b    = blk & (NB - 1);    // XCD affinity (blockIdx % 8 round-robin)
  const int g    = blk >> 3;
  const int tid  = threadIdx.x;
  const int lane = tid & 63;
  const int wave = tid >> 6;
  const float4* p = pts + (size_t)b * NP;
  const int len = lengths[b];
  const float4 cc = centers_ws[b * NG + g];

  __shared__ u64 masks[256];          // per-64-chunk in-radius bitmasks
  __shared__ u32 scnt[256];
  __shared__ u32 spre[256];
  __shared__ u32 swsum[4];
  __shared__ float candE[UPK];
  __shared__ int   candI[UPK];
  __shared__ int   s_T, s_pl;
  __shared__ int   s_win[GS];

  if (g >= CTX) {                     // count-only: is this group full?
    u32 c = 0;
    for (int step = 0; step < 64; step++) {
      int i = step * 256 + tid;
      if (i < len) {
        float4 q = p[i];
        float d = dist2(cc.x, cc.y, cc.z, q.x, q.y, q.z);
        c += (d < 0.25f) ? 1u : 0u;
      }
    }
#pragma unroll
    for (int off = 32; off; off >>= 1) c += __shfl_down(c, (unsigned)off, 64);
    if (lane == 0) swsum[wave] = c;
    __syncthreads();
    if (tid == 0) {
      u32 total = swsum[0] + swsum[1] + swsum[2] + swsum[3];
      if (total >= GS) atomicAdd(&group_len[b], 1);
    }
    return;
  }

  // Pass 1: in-radius flags, index order preserved via ballot
  for (int step = 0; step < 64; step++) {
    int i = step * 256 + tid;         // chunk = step*4 + wave, bit = lane
    bool flag = false;
    if (i < len) {
      float4 q = p[i];
      float d = dist2(cc.x, cc.y, cc.z, q.x, q.y, q.z);
      flag = d < 0.25f;               // radius^2, strict <
    }
    u64 m = __ballot(flag);
    if (lane == 0) masks[step * 4 + wave] = m;
  }
  __syncthreads();

  // Prefix scan over 256 chunk counts: shfl_up within wave + 4-wave offset
  u32 cnt = (u32)__popcll(masks[tid]);
  u32 s = cnt;
#pragma unroll
  for (int off = 1; off < 64; off <<= 1) {
    u32 o = __shfl_up(s, (unsigned)off, 64);
    if (lane >= off) s += o;
  }
  if (lane == 63) swsum[wave] = s;
  __syncthreads();
  u32 woff = 0;
#pragma unroll
  for (int w = 0; w < 4; w++) woff += (w < wave) ? swsum[w] : 0u;
  const u32 total = swsum[0] + swsum[1] + swsum[2] + swsum[3];
  const u32 incl = s + woff;          // block-inclusive prefix for chunk tid
  scnt[tid] = cnt;
  spre[tid] = incl;

  // Cap index T: index of the (UPK-1)-ranked in-radius point (first-512 rule)
  if (total > UPK) {
    u32 ex = incl - cnt;
    if (ex <= (UPK - 1) && incl > (UPK - 1)) {        // exactly one thread
      u32 r = (UPK - 1) - ex;
      u64 m = masks[tid];
      for (u32 k = 0; k < r; k++) m &= m - 1;
      s_T = tid * 64 + ((int)__ffsll((unsigned long long)m) - 1);
    }
  } else if (tid == 0) {
    s_T = NP - 1;
  }
  __syncthreads();                    // covers spre/scnt/s_T
  const int T = s_T;

  // Pass 2: compact (energy, idx) of candidates into LDS at exact rank
  for (int step = 0; step < 64; step++) {
    int i  = step * 256 + tid;
    int ch = step * 4 + wave;
    u64 m = masks[ch];
    if (((m >> lane) & 1ull) && i <= T) {
      u32 pos = ((spre[ch] - scnt[ch]) +
                 (u32)__popcll(m & ((1ull << lane) - 1ull))) & (UPK - 1);
      candE[pos] = ((const float*)p)[i * 4 + 3];   // energy channel
      candI[pos] = i;
    }
  }
  __syncthreads();

  const int ncand = (int)(total < UPK ? total : UPK);

  // Top-32 by (energy desc, pos asc): single wave, barrier-free rounds
  if (wave == 0) {
    u64 k[8];
#pragma unroll
    for (int t = 0; t < 8; t++) {
      int ci = lane + t * 64;
      k[t] = (ci < ncand) ? (((u64)fkey(candE[ci]) << 32) | (u32)(~ci)) : 0ull;
    }
    int pl = 0;
    for (int r = 0; r < GS; r++) {
      u64 bm = k[0];
#pragma unroll
      for (int t = 1; t < 8; t++) if (k[t] > bm) bm = k[t];
#pragma unroll
      for (int off = 32; off; off >>= 1) {
        u64 o = __shfl_xor(bm, (unsigned)off, 64);
        if (o > bm) bm = o;
      }
      if (bm == 0) break;             // wave-uniform: no candidates left
      int pos = (int)(~(u32)bm) & (UPK - 1);
      if (lane == 0) s_win[r] = candI[pos];
      int ol = pos & 63, ot = pos >> 6;
#pragma unroll
      for (int t = 0; t < 8; t++)     // kill winner (owner = lane ol, slot ot)
        if (t == ot && lane == ol) k[t] = 0;
      pl = r + 1;
    }
    if (lane == 0) {
      int f0 = (pl > 0) ? s_win[0] : 0;   // fill_empty_indices (pl>=1 always:
      for (int r = pl; r < GS; r++) s_win[r] = f0;  // center is in-radius)
      s_pl = pl;
    }
  }
  __syncthreads();

  const int base = b * CTX + g;
  if (tid < GS) {
    int fi = s_win[tid] & (NP - 1);
    float4 q = p[fi];
    ((float4*)out)[base * GS + tid] = q;
    out[OFF_PMASK + base * GS + tid] = (tid < s_pl) ? 1.0f : 0.0f;
  }
  if (tid == 0 && total >= GS) atomicAdd(&group_len[b], 1);
}

// ---------------------------------------------------------------------------
// Kernel 3: embedding mask from full-group counts
// ---------------------------------------------------------------------------
__global__ void emb_kernel(const int* __restrict__ group_len,
                           float* __restrict__ out)
{
  int i = blockIdx.x * blockDim.x + threadIdx.x;
  if (i < NB * CTX) {
    int b = i >> 8;
    int g = i & 255;
    out[OFF_EMB + i] = (g < group_len[b]) ? 1.0f : 0.0f;
  }
}

extern "C" void kernel_launch(void* const* d_in, const int* in_sizes, int n_in,
                              void* d_out, int out_size, void* d_ws, size_t ws_size,
                              hipStream_t stream)
{
  const float4* pts     = (const float4*)d_in[0];   // f32 (B,N,4)
  const int*    lengths = (const int*)d_in[1];
  float* out = (float*)d_out;

  float4* centers_ws = (float4*)d_ws;               // 8*512*16 B = 64 KB
  int*    group_len  = (int*)((char*)d_ws + (size_t)NB * NG * sizeof(float4));

  fps_kernel<<<NB, FPS_T, 0, stream>>>(pts, lengths, centers_ws, group_len, out);
  group_kernel<<<NB * NG, BQ_T, 0, stream>>>(pts, lengths, centers_ws, group_len, out);
  emb_kernel<<<(NB * CTX + 255) / 256, 256, 0, stream>>>(group_len, out);
}